// Round 6
// baseline (2237.049 us; speedup 1.0000x reference)
//
#include <hip/hip_runtime.h>

// LSTM T=512 B=256 NP=34 H=512 NT=16.
// R9: dual-group latency hiding. 256 blocks = 8 group-pairs x 32 col-slices
// (16 h-cols each). Each block advances TWO independent batch-group
// recurrences (gA=2p, gB=2p+1) in alternating phases; each group's
// publish->visibility->poll latency hides under the other group's compute.
// W slice (64 rows x 512, LDS 64KB) + x-fragments + biases are shared by
// both groups (they depend only on the col-slice). Poll = issue-early
// (inline asm, no wait) at phase start of the OTHER group, check-late
// behind s_waitcnt+sched_barrier one phase later; R8's pipelined
// load8_coh round is the spin fallback. Protocol unchanged (sentinel,
// write-once u64, relaxed agent stores).
#define TT 512
#define BT 256
#define NP 34
#define HH 512
#define SENT 0xAAAAAAAAu

typedef short bf16x8 __attribute__((ext_vector_type(8)));
typedef float f32x4 __attribute__((ext_vector_type(4)));

static __device__ __forceinline__ unsigned short f2bf(float x) {
  unsigned int u = __float_as_uint(x);
  return (unsigned short)((u + 0x7fffu + ((u >> 16) & 1u)) >> 16);
}

template <int CTRL>
static __device__ __forceinline__ float dppq(float x) {
  return __int_as_float(
      __builtin_amdgcn_mov_dpp(__float_as_int(x), CTRL, 0xF, 0xF, true));
}

static __device__ __forceinline__ float rcpf(float x) {
  return __builtin_amdgcn_rcpf(x);
}

// Issue 8 coherence-point u64 loads, NO wait (results read a phase later).
static __device__ __forceinline__ void issue8(const unsigned long long* p,
                                              unsigned long long o[8]) {
  asm volatile(
      "global_load_dwordx2 %0, %8, off sc0 sc1\n\t"
      "global_load_dwordx2 %1, %9, off sc0 sc1\n\t"
      "global_load_dwordx2 %2, %10, off sc0 sc1\n\t"
      "global_load_dwordx2 %3, %11, off sc0 sc1\n\t"
      "global_load_dwordx2 %4, %12, off sc0 sc1\n\t"
      "global_load_dwordx2 %5, %13, off sc0 sc1\n\t"
      "global_load_dwordx2 %6, %14, off sc0 sc1\n\t"
      "global_load_dwordx2 %7, %15, off sc0 sc1"
      : "=&v"(o[0]), "=&v"(o[1]), "=&v"(o[2]), "=&v"(o[3]),
        "=&v"(o[4]), "=&v"(o[5]), "=&v"(o[6]), "=&v"(o[7])
      : "v"(p), "v"(p + 256), "v"(p + 512), "v"(p + 768),
        "v"(p + 1024), "v"(p + 1280), "v"(p + 1536), "v"(p + 1792)
      : "memory");
}

// One full poll round: 8 pipelined loads + single waitcnt (R8-proven).
static __device__ __forceinline__ void load8_coh(const unsigned long long* p,
                                                 unsigned long long o[8]) {
  asm volatile(
      "global_load_dwordx2 %0, %8, off sc0 sc1\n\t"
      "global_load_dwordx2 %1, %9, off sc0 sc1\n\t"
      "global_load_dwordx2 %2, %10, off sc0 sc1\n\t"
      "global_load_dwordx2 %3, %11, off sc0 sc1\n\t"
      "global_load_dwordx2 %4, %12, off sc0 sc1\n\t"
      "global_load_dwordx2 %5, %13, off sc0 sc1\n\t"
      "global_load_dwordx2 %6, %14, off sc0 sc1\n\t"
      "global_load_dwordx2 %7, %15, off sc0 sc1\n\t"
      "s_waitcnt vmcnt(0)"
      : "=&v"(o[0]), "=&v"(o[1]), "=&v"(o[2]), "=&v"(o[3]),
        "=&v"(o[4]), "=&v"(o[5]), "=&v"(o[6]), "=&v"(o[7])
      : "v"(p), "v"(p + 256), "v"(p + 512), "v"(p + 768),
        "v"(p + 1024), "v"(p + 1280), "v"(p + 1536), "v"(p + 1792)
      : "memory");
}

static __device__ __forceinline__ unsigned validmask8(
    const unsigned long long o[8]) {
  unsigned ok = 1u;
#pragma unroll
  for (int u = 0; u < 8; ++u) {
    unsigned long long x = o[u];
    ok &= (((unsigned)x != SENT) & ((unsigned)(x >> 32) != SENT)) ? 1u : 0u;
  }
  return ok;
}

// LDS (131072 B dynamic):
//   [0, 65536)         Whh slice bf16 [64 rows][512], 16B-chunk swizzle
//                      phys_chunk = c ^ (r&7). Row r = j*4+q (j=local col, q=gate).
//   [65536, 98304)     group-A h-stage bf16 2x[16][512] (parity dbuf)
//   [98304, 131072)    group-B h-stage bf16 2x[16][512]
__global__ void __launch_bounds__(256, 1) lstm_coop(
    const float* __restrict__ Whh, const float* __restrict__ Wih,
    const float* __restrict__ bih, const float* __restrict__ bhh,
    const unsigned short* __restrict__ Ax,  // [T][256][64] bf16: [points(34),0..]
    unsigned short* hs)                     // [T][256][512] bf16, pre-set SENT
{
  extern __shared__ char smem[];
  unsigned short* Wl = (unsigned short*)smem;
  unsigned short* stgA = (unsigned short*)(smem + 65536);
  unsigned short* stgB = (unsigned short*)(smem + 98304);

  const int tid = threadIdx.x;
  const int n2 = blockIdx.x & 31;  // col-slice: cols [n2*16, n2*16+16)
  const int p = blockIdx.x >> 5;   // group pair: gA=2p, gB=2p+1
  const int bbA = p * 32;
  const int bbB = p * 32 + 16;

  // ---- init resident Whh slice (swizzled, rows r = j*4+q, 64 rows) ----
  for (int idx = tid; idx < 64 * 512; idx += 256) {
    int r = idx >> 9, k = idx & 511;
    int grow = (r & 3) * 512 + n2 * 16 + (r >> 2);
    float v = Whh[(size_t)grow * 512 + k];
    int c = k >> 3;
    Wl[r * 512 + ((c ^ (r & 7)) << 3) + (k & 7)] = f2bf(v);
  }

  const int lane = tid & 63;
  const int w = tid >> 6;        // wave: local cols [4w, 4w+4), all 4 gates
  const int m = lane & 15;       // A row (batch) / B tile-row
  const int ko = lane >> 4;      // k-subgroup
  const int r0 = 16 * w + m;     // W row for B fragment
  const int q = m & 3;           // gate owned by this lane
  const int jj = m >> 2;         // col-in-wave
  const int col = n2 * 16 + 4 * w + jj;  // this lane's global h col
  const int mx = m & 7;
  const bool q0 = (q == 0), q1 = (q == 1), q2 = (q == 2);

  // biases for all 4 gates at this lane's col
  float bi[4];
#pragma unroll
  for (int gg = 0; gg < 4; ++gg) {
    int gr = gg * 512 + col;
    bi[gg] = bih[gr] + bhh[gr];
  }

  // x-slice W fragments for B row r0 (gate q', col j'): shared by both groups
  bf16x8 bxa, bxb;
  {
    int grow = (r0 & 3) * 512 + n2 * 16 + (r0 >> 2);
#pragma unroll
    for (int e = 0; e < 8; ++e) {
      int ka = 8 * ko + e;
      int kb = 32 + 8 * ko + e;
      bxa[e] = (short)f2bf(Wih[grow * 34 + ka]);
      bxb[e] = (kb < NP) ? (short)f2bf(Wih[grow * 34 + kb]) : (short)0;
    }
  }
  __syncthreads();  // Wl ready (read-only hereafter)

  float ccA = 0.f, ccB = 0.f;
  unsigned long long pollA[8], pollB[8];

  // prologue: x fragments for t=0, group A
  bf16x8 xvA0, xvA1, xvB0, xvB1;
  {
    const unsigned short* xb = Ax + ((size_t)0 * BT + bbA + m) * 64;
    xvA0 = *(const bf16x8*)(xb + (ko << 3));
    xvA1 = *(const bf16x8*)(xb + 32 + (ko << 3));
  }

  for (int t = 0; t < TT; ++t) {
    // ================= Phase A =================
    unsigned long long* hv = pollA;
    if (t > 0) {
      const unsigned long long* pb =
          (const unsigned long long*)(hs + ((size_t)(t - 1) * BT + bbA) * HH) + tid;
      asm volatile("s_waitcnt vmcnt(0)" ::: "memory");
      __builtin_amdgcn_sched_barrier(0);
      if (!validmask8(pollA)) {
        int guard = 0;
        for (;;) {
          load8_coh(pb, pollA);
          if (validmask8(pollA)) break;
          if (++guard > (1 << 18)) break;
        }
      }
    } else {
#pragma unroll
      for (int u = 0; u < 8; ++u) pollA[u] = 0ull;
    }
    // stage into LDS (swizzled)
    unsigned short* st = stgA + (t & 1) * 8192;
#pragma unroll
    for (int u = 0; u < 8; ++u) {
      int idx = u * 256 + tid;
      int mm = idx >> 7, cu = idx & 127;
      int c16 = cu >> 1, half = cu & 1;
      *(unsigned long long*)&st[mm * 512 + ((c16 ^ (mm & 7)) << 3) + (half << 2)] = hv[u];
    }
    __syncthreads();
    // issue group-B poll for h_B(t-1); checked at phase B (one phase of cover)
    if (t > 0) {
      const unsigned long long* pb =
          (const unsigned long long*)(hs + ((size_t)(t - 1) * BT + bbB) * HH) + tid;
      issue8(pb, pollB);
    }
    // prefetch group-B x fragments for this t (used next phase)
    {
      const unsigned short* xb = Ax + ((size_t)t * BT + bbB + m) * 64;
      xvB0 = *(const bf16x8*)(xb + (ko << 3));
      xvB1 = *(const bf16x8*)(xb + 32 + (ko << 3));
    }
    // ---- GEMM A: h (K=512, 2 chains) + x at the end ----
    {
      f32x4 aa = {0.f, 0.f, 0.f, 0.f}, ab = {0.f, 0.f, 0.f, 0.f};
#pragma unroll
      for (int s = 0; s < 16; ++s) {
        int cs = (((4 * s + ko) ^ mx) << 3);
        bf16x8 av = *(const bf16x8*)&st[m * 512 + cs];
        bf16x8 bv = *(const bf16x8*)&Wl[r0 * 512 + cs];
        if (s & 1) ab = __builtin_amdgcn_mfma_f32_16x16x32_bf16(av, bv, ab, 0, 0, 0);
        else       aa = __builtin_amdgcn_mfma_f32_16x16x32_bf16(av, bv, aa, 0, 0, 0);
      }
      aa = __builtin_amdgcn_mfma_f32_16x16x32_bf16(xvA0, bxa, aa, 0, 0, 0);
      ab = __builtin_amdgcn_mfma_f32_16x16x32_bf16(xvA1, bxb, ab, 0, 0, 0);
      f32x4 A = aa + ab;
      // quad gather -> gates for cell (batch 4ko+q, col)
      float own = q0 ? A.x : q1 ? A.y : q2 ? A.z : A.w;
      float t1s = q0 ? A.w : q1 ? A.x : q2 ? A.y : A.z;
      float t2s = q0 ? A.z : q1 ? A.w : q2 ? A.x : A.y;
      float t3s = q0 ? A.y : q1 ? A.z : q2 ? A.w : A.x;
      float r1 = dppq<0x39>(t1s);
      float r2 = dppq<0x4E>(t2s);
      float r3 = dppq<0x93>(t3s);
      float gi = (q0 ? own : q1 ? r3 : q2 ? r2 : r1) + bi[0];
      float gf = (q0 ? r1 : q1 ? own : q2 ? r3 : r2) + bi[1];
      float gg = (q0 ? r2 : q1 ? r1 : q2 ? own : r3) + bi[2];
      float go = (q0 ? r3 : q1 ? r2 : q2 ? r1 : own) + bi[3];
      float ii = rcpf(1.f + __expf(-gi));
      float ff = rcpf(1.f + __expf(-gf));
      float tg = 2.f * rcpf(1.f + __expf(-2.f * gg)) - 1.f;
      float oo = rcpf(1.f + __expf(-go));
      ccA = ff * ccA + ii * tg;
      float h = oo * (2.f * rcpf(1.f + __expf(-2.f * ccA)) - 1.f);
      // pack 4 cols -> one u64 (xor4: jj^1 pair; xor8: jj^2 merge)
      float hp = __shfl_xor(h, 4);
      unsigned pr = (unsigned)f2bf(h) | ((unsigned)f2bf(hp) << 16);
      unsigned sr = (unsigned)__shfl_xor((int)pr, 8);
      if (jj == 0) {
        unsigned long long val = (((unsigned long long)sr << 32) | pr);
        size_t uidx = ((size_t)t * BT + bbA + 4 * ko + q) * 128 + 4 * n2 + w;
        __hip_atomic_store((unsigned long long*)hs + uidx, val,
                           __ATOMIC_RELAXED, __HIP_MEMORY_SCOPE_AGENT);
      }
    }

    // ================= Phase B =================
    hv = pollB;
    if (t > 0) {
      const unsigned long long* pb =
          (const unsigned long long*)(hs + ((size_t)(t - 1) * BT + bbB) * HH) + tid;
      asm volatile("s_waitcnt vmcnt(0)" ::: "memory");
      __builtin_amdgcn_sched_barrier(0);
      if (!validmask8(pollB)) {
        int guard = 0;
        for (;;) {
          load8_coh(pb, pollB);
          if (validmask8(pollB)) break;
          if (++guard > (1 << 18)) break;
        }
      }
    } else {
#pragma unroll
      for (int u = 0; u < 8; ++u) pollB[u] = 0ull;
    }
    st = stgB + (t & 1) * 8192;
#pragma unroll
    for (int u = 0; u < 8; ++u) {
      int idx = u * 256 + tid;
      int mm = idx >> 7, cu = idx & 127;
      int c16 = cu >> 1, half = cu & 1;
      *(unsigned long long*)&st[mm * 512 + ((c16 ^ (mm & 7)) << 3) + (half << 2)] = hv[u];
    }
    __syncthreads();
    // issue group-A poll for h_A(t) (just published around now everywhere);
    // checked at phase A of t+1 -> one full phase of latency cover
    {
      const unsigned long long* pb =
          (const unsigned long long*)(hs + ((size_t)t * BT + bbA) * HH) + tid;
      issue8(pb, pollA);
    }
    // prefetch group-A x fragments for t+1
    {
      int tn = (t + 1 < TT) ? t + 1 : t;
      const unsigned short* xb = Ax + ((size_t)tn * BT + bbA + m) * 64;
      xvA0 = *(const bf16x8*)(xb + (ko << 3));
      xvA1 = *(const bf16x8*)(xb + 32 + (ko << 3));
    }
    // ---- GEMM B ----
    {
      f32x4 aa = {0.f, 0.f, 0.f, 0.f}, ab = {0.f, 0.f, 0.f, 0.f};
#pragma unroll
      for (int s = 0; s < 16; ++s) {
        int cs = (((4 * s + ko) ^ mx) << 3);
        bf16x8 av = *(const bf16x8*)&st[m * 512 + cs];
        bf16x8 bv = *(const bf16x8*)&Wl[r0 * 512 + cs];
        if (s & 1) ab = __builtin_amdgcn_mfma_f32_16x16x32_bf16(av, bv, ab, 0, 0, 0);
        else       aa = __builtin_amdgcn_mfma_f32_16x16x32_bf16(av, bv, aa, 0, 0, 0);
      }
      aa = __builtin_amdgcn_mfma_f32_16x16x32_bf16(xvB0, bxa, aa, 0, 0, 0);
      ab = __builtin_amdgcn_mfma_f32_16x16x32_bf16(xvB1, bxb, ab, 0, 0, 0);
      f32x4 A = aa + ab;
      float own = q0 ? A.x : q1 ? A.y : q2 ? A.z : A.w;
      float t1s = q0 ? A.w : q1 ? A.x : q2 ? A.y : A.z;
      float t2s = q0 ? A.z : q1 ? A.w : q2 ? A.x : A.y;
      float t3s = q0 ? A.y : q1 ? A.z : q2 ? A.w : A.x;
      float r1 = dppq<0x39>(t1s);
      float r2 = dppq<0x4E>(t2s);
      float r3 = dppq<0x93>(t3s);
      float gi = (q0 ? own : q1 ? r3 : q2 ? r2 : r1) + bi[0];
      float gf = (q0 ? r1 : q1 ? own : q2 ? r3 : r2) + bi[1];
      float gg = (q0 ? r2 : q1 ? r1 : q2 ? own : r3) + bi[2];
      float go = (q0 ? r3 : q1 ? r2 : q2 ? r1 : own) + bi[3];
      float ii = rcpf(1.f + __expf(-gi));
      float ff = rcpf(1.f + __expf(-gf));
      float tg = 2.f * rcpf(1.f + __expf(-2.f * gg)) - 1.f;
      float oo = rcpf(1.f + __expf(-go));
      ccB = ff * ccB + ii * tg;
      float h = oo * (2.f * rcpf(1.f + __expf(-2.f * ccB)) - 1.f);
      float hp = __shfl_xor(h, 4);
      unsigned pr = (unsigned)f2bf(h) | ((unsigned)f2bf(hp) << 16);
      unsigned sr = (unsigned)__shfl_xor((int)pr, 8);
      if (jj == 0) {
        unsigned long long val = (((unsigned long long)sr << 32) | pr);
        size_t uidx = ((size_t)t * BT + bbB + 4 * ko + q) * 128 + 4 * n2 + w;
        __hip_atomic_store((unsigned long long*)hs + uidx, val,
                           __ATOMIC_RELAXED, __HIP_MEMORY_SCOPE_AGENT);
      }
    }
  }
}

// Ax[t][b][k] = bf16(points[t][b][k]) for k<34 else 0
__global__ void __launch_bounds__(256) prep_ax(const float* __restrict__ pts,
                                               unsigned short* __restrict__ Ax) {
  size_t i = (size_t)blockIdx.x * 256 + threadIdx.x;  // [0, 512*256*64)
  int k = (int)(i & 63);
  size_t tb = i >> 6;
  float v = (k < NP) ? pts[tb * NP + k] : 0.f;
  Ax[i] = f2bf(v);
}

// logits = hs @ W_lin^T + b_lin ; softmax over 16
__global__ void __launch_bounds__(256) head_kernel(const unsigned short* __restrict__ hs,
                                                   const float* __restrict__ Wlin,
                                                   const float* __restrict__ blin,
                                                   float* __restrict__ out) {
  __shared__ float wl[16 * 513];
  __shared__ float bl[16];
  __shared__ unsigned short hl[16 * 520];
  const int tid = threadIdx.x;
  for (int i = tid; i < 16 * 512; i += 256) wl[(i >> 9) * 513 + (i & 511)] = Wlin[i];
  if (tid < 16) bl[tid] = blin[tid];
  const size_t Rb = (size_t)blockIdx.x * 16;  // 16 rows of [131072][512]
  const uint4* gsrc = (const uint4*)(hs + Rb * 512);
#pragma unroll
  for (int j = 0; j < 4; ++j) {
    int e8 = tid + 256 * j;  // uint4 index, 8 bf16 each
    uint4 v = gsrc[e8];
    int r = e8 >> 6, k = (e8 & 63) << 3;
    *(uint4*)&hl[r * 520 + k] = v;
  }
  __syncthreads();
  const int r = tid >> 4, tg = tid & 15;
  float acc = bl[tg];
  const float* wp = &wl[tg * 513];
#pragma unroll 4
  for (int k8 = 0; k8 < 64; ++k8) {
    uint4 hv = *(const uint4*)&hl[r * 520 + (k8 << 3)];
    const float* w8 = wp + (k8 << 3);
    acc += __uint_as_float(hv.x << 16) * w8[0];
    acc += __uint_as_float(hv.x & 0xffff0000u) * w8[1];
    acc += __uint_as_float(hv.y << 16) * w8[2];
    acc += __uint_as_float(hv.y & 0xffff0000u) * w8[3];
    acc += __uint_as_float(hv.z << 16) * w8[4];
    acc += __uint_as_float(hv.z & 0xffff0000u) * w8[5];
    acc += __uint_as_float(hv.w << 16) * w8[6];
    acc += __uint_as_float(hv.w & 0xffff0000u) * w8[7];
  }
  float mx = acc;
#pragma unroll
  for (int d = 8; d; d >>= 1) mx = fmaxf(mx, __shfl_xor(mx, d, 16));
  float e = __expf(acc - mx);
  float sm = e;
#pragma unroll
  for (int d = 8; d; d >>= 1) sm += __shfl_xor(sm, d, 16);
  out[Rb * 16 + tid] = e / sm;
}

extern "C" void kernel_launch(void* const* d_in, const int* in_sizes, int n_in,
                              void* d_out, int out_size, void* d_ws, size_t ws_size,
                              hipStream_t stream) {
  (void)in_sizes; (void)n_in; (void)out_size; (void)ws_size;
  const float* pts  = (const float*)d_in[0];
  const float* Wih  = (const float*)d_in[1];
  const float* Whh  = (const float*)d_in[2];
  const float* bih  = (const float*)d_in[3];
  const float* bhh  = (const float*)d_in[4];
  const float* Wlin = (const float*)d_in[5];
  const float* blin = (const float*)d_in[6];
  float* out = (float*)d_out;
  char* ws = (char*)d_ws;
  // ws layout: hs 134217728 B | Ax 16777216 B
  unsigned short* hs = (unsigned short*)ws;
  unsigned short* Ax = (unsigned short*)(ws + 134217728);

  // sentinel-fill hs (self-validating exchange protocol needs every launch)
  hipMemsetAsync(hs, 0xAA, 134217728, stream);
  prep_ax<<<32768, 256, 0, stream>>>(pts, Ax);
  (void)hipFuncSetAttribute((const void*)lstm_coop,
                            hipFuncAttributeMaxDynamicSharedMemorySize, 131072);
  void* args[6];
  args[0] = (void*)&Whh; args[1] = (void*)&Wih; args[2] = (void*)&bih;
  args[3] = (void*)&bhh; args[4] = (void*)&Ax;  args[5] = (void*)&hs;
  hipLaunchCooperativeKernel((void*)lstm_coop, dim3(256), dim3(256), args, 131072, stream);
  head_kernel<<<8192, 256, 0, stream>>>(hs, Wlin, blin, out);
}